// Round 10
// baseline (346.658 us; speedup 1.0000x reference)
//
#include <hip/hip_runtime.h>

#define N_NODES 100000
#define N_EDGES 1600000
#define N_GRAPHS 1000

#define NB_C 391                 // coarse buckets: dst>>8, 256 nodes each
#define B1   1024                // blocks in count/scatter phases
#define CHUNK_E ((N_EDGES + B1 - 1) / B1)   // 1563
#define STG_MAX 4736             // finalize LDS staging capacity (mean 4096, sd 64)
#define GEMM_BLK ((N_NODES + 63) / 64)      // 1563

typedef unsigned int uint32;
typedef unsigned short ushort16;
typedef __attribute__((ext_vector_type(8))) short short8;   // 8 bf16 (4 VGPRs)
typedef __attribute__((ext_vector_type(4))) float f32x4;    // MFMA C/D

// float -> bf16 with round-to-nearest-even
static __device__ __forceinline__ ushort16 f2bf(float f) {
    uint32 u = __float_as_uint(f);
    u += 0x7fffu + ((u >> 16) & 1u);
    return (ushort16)(u >> 16);
}
static __device__ __forceinline__ uint32 pk2(float a, float b) {
    return (uint32)f2bf(a) | ((uint32)f2bf(b) << 16);
}
// unpack a bf16x2 word into two floats
static __device__ __forceinline__ void bf2x(uint32 v, float& lo, float& hi) {
    lo = __uint_as_float(v << 16);
    hi = __uint_as_float(v & 0xffff0000u);
}
// accumulate a 16B chunk (8 bf16) into a[0..7]
static __device__ __forceinline__ void acc8(float* a, uint4 v) {
    float lo, hi;
    bf2x(v.x, lo, hi); a[0] += lo; a[1] += hi;
    bf2x(v.y, lo, hi); a[2] += lo; a[3] += hi;
    bf2x(v.z, lo, hi); a[4] += lo; a[5] += hi;
    bf2x(v.w, lo, hi); a[6] += lo; a[7] += hi;
}

union CV8 { uint4 u; short8 s; };

// ============ K0: weight pre-pass (separate launch — gemm1 consumes W1t) ============
__global__ __launch_bounds__(256) void convw_kernel(
    const float* __restrict__ W1, const float* __restrict__ W2,
    const float* __restrict__ W3,
    ushort16* __restrict__ W1t, ushort16* __restrict__ W2t,
    ushort16* __restrict__ W3t)
{
    int t = threadIdx.x;
    if (blockIdx.x == 0) {
        for (int i = t; i < 64 * 128; i += 256) {
            int j = i >> 7, k = i & 127;          // W1t[j][k] (64 x 128)
            W1t[i] = f2bf(W1[k * 64 + j]);
        }
    } else if (blockIdx.x == 1) {
        for (int i = t; i < 64 * 64; i += 256) {
            int j = i >> 6, k = i & 63;
            W2t[i] = f2bf(W2[k * 64 + j]);
        }
    } else {
        for (int i = t; i < 64 * 64; i += 256) {
            int j = i >> 6, k = i & 63;
            W3t[i] = f2bf(W3[k * 64 + j]);
        }
    }
}

// ============ K1: global count (blocks 0..B1-1) + gemm1 (rest) — independent ============
__global__ __launch_bounds__(256) void k1_combined_kernel(
    const int* __restrict__ dst, int* __restrict__ cnt_g,
    const float* __restrict__ x, const ushort16* __restrict__ W1t,
    ushort16* __restrict__ y)
{
    int b = blockIdx.x, t = threadIdx.x;
    if (b < B1) {
        // ---- count: LDS histogram -> global bucket counters ----
        __shared__ int cnt[NB_C];
        for (int q = t; q < NB_C; q += 256) cnt[q] = 0;
        __syncthreads();
        int e0 = b * CHUNK_E;
        int e1 = e0 + CHUNK_E; if (e1 > N_EDGES) e1 = N_EDGES;
        for (int e = e0 + t; e < e1; e += 256)
            atomicAdd(&cnt[dst[e] >> 8], 1);
        __syncthreads();
        for (int q = t; q < NB_C; q += 256)
            if (cnt[q] > 0) atomicAdd(&cnt_g[q], cnt[q]);
        return;
    }
    // ---- gemm1: y(bf16) = x(fp32->bf16) @ W1, 16 nodes x 64 outs per wave ----
    {
        int lane = t & 63;
        int wave = t >> 6;
        int col = lane & 15, quad = lane >> 4;
        int node0 = (b - B1) * 64 + wave * 16;
        int anode = node0 + col;

        short8 a[4];
        if (anode < N_NODES) {
            const float* xr = &x[(size_t)anode * 128 + quad * 8];
#pragma unroll
            for (int s = 0; s < 4; ++s) {
                float4 v0 = *(const float4*)&xr[s * 32];
                float4 v1 = *(const float4*)&xr[s * 32 + 4];
                CV8 cv;
                cv.u = make_uint4(pk2(v0.x, v0.y), pk2(v0.z, v0.w),
                                  pk2(v1.x, v1.y), pk2(v1.z, v1.w));
                a[s] = cv.s;
            }
        } else {
            short8 z = {0, 0, 0, 0, 0, 0, 0, 0};
#pragma unroll
            for (int s = 0; s < 4; ++s) a[s] = z;
        }

        f32x4 acc[4];
#pragma unroll
        for (int nt = 0; nt < 4; ++nt)
#pragma unroll
            for (int r = 0; r < 4; ++r) acc[nt][r] = 0.0f;

#pragma unroll
        for (int nt = 0; nt < 4; ++nt) {
            const ushort16* wr = &W1t[(size_t)(nt * 16 + col) * 128 + quad * 8];
#pragma unroll
            for (int s = 0; s < 4; ++s) {
                short8 bb8 = *(const short8*)&wr[s * 32];
                acc[nt] = __builtin_amdgcn_mfma_f32_16x16x32_bf16(a[s], bb8, acc[nt], 0, 0, 0);
            }
        }

#pragma unroll
        for (int nt = 0; nt < 4; ++nt)
#pragma unroll
            for (int r = 0; r < 4; ++r) {
                int node = node0 + quad * 4 + r;
                if (node < N_NODES)
                    y[(size_t)node * 64 + nt * 16 + col] = f2bf(acc[nt][r]);
            }
    }
}

// ============ K2: tiny scan over 391 bucket counts -> bstart[392], gcur ============
__global__ __launch_bounds__(512) void scan_bins_kernel(
    const int* __restrict__ cnt_g, int* __restrict__ bstart, int* __restrict__ gcur)
{
    __shared__ int s[512];
    int t = threadIdx.x;
    int v = (t < NB_C) ? cnt_g[t] : 0;
    s[t] = v;
    __syncthreads();
    for (int off = 1; off < 512; off <<= 1) {
        int x = (t >= off) ? s[t - off] : 0;
        __syncthreads();
        s[t] += x;
        __syncthreads();
    }
    if (t < NB_C) {
        int excl = s[t] - v;
        bstart[t] = excl;
        gcur[t] = excl;
    }
    if (t == 0) bstart[NB_C] = N_EDGES;
}

// ============ K3: scatter — block-local LDS sort + atomic range reservation ============
// Payload: ((dst & 255) << 17) | src   (src < 2^17)
__global__ __launch_bounds__(256) void scatter_kernel(
    const int* __restrict__ src, const int* __restrict__ dst,
    int* __restrict__ gcur, uint32* __restrict__ tmp)
{
    __shared__ int cnt[NB_C];
    __shared__ int loc[NB_C];
    __shared__ int cur[NB_C];
    __shared__ int msb[NB_C];
    __shared__ int ssum[256];
    __shared__ uint32 staged[CHUNK_E];
    __shared__ unsigned short bkt[CHUNK_E];
    int b = blockIdx.x, t = threadIdx.x;
    int e0 = b * CHUNK_E;
    int e1 = e0 + CHUNK_E; if (e1 > N_EDGES) e1 = N_EDGES;
    int n = e1 - e0;

    for (int q = t; q < NB_C; q += 256) cnt[q] = 0;
    __syncthreads();
    for (int e = e0 + t; e < e1; e += 256)
        atomicAdd(&cnt[dst[e] >> 8], 1);
    __syncthreads();
    // reserve this block's output range in each bucket (latency hidden under scan)
    for (int q = t; q < NB_C; q += 256)
        msb[q] = atomicAdd(&gcur[q], cnt[q]);
    // parallel exclusive scan over NB_C bins: thread t owns bins {2t, 2t+1}
    int q0 = 2 * t, q1 = 2 * t + 1;
    int c0 = (q0 < NB_C) ? cnt[q0] : 0;
    int c1 = (q1 < NB_C) ? cnt[q1] : 0;
    int pairsum = c0 + c1;
    ssum[t] = pairsum;
    __syncthreads();
    for (int off = 1; off < 256; off <<= 1) {
        int x = (t >= off) ? ssum[t - off] : 0;
        __syncthreads();
        ssum[t] += x;
        __syncthreads();
    }
    int excl = ssum[t] - pairsum;
    if (q0 < NB_C) { loc[q0] = excl; cur[q0] = excl; }
    if (q1 < NB_C) { loc[q1] = excl + c0; cur[q1] = excl + c0; }
    __syncthreads();
    // place edges bucket-sorted into LDS; remember bucket id per slot
    for (int e = e0 + t; e < e1; e += 256) {
        int d = dst[e];
        int q = d >> 8;
        int pos = atomicAdd(&cur[q], 1);
        staged[pos] = ((uint32)(d & 255) << 17) | (uint32)src[e];
        bkt[pos] = (unsigned short)q;
    }
    __syncthreads();
    // copy-out: consecutive lanes -> consecutive global addresses within runs
    for (int i = t; i < n; i += 256) {
        int q = bkt[i];
        tmp[msb[q] + (i - loc[q])] = staged[i];
    }
}

// ============ K4: finalize — per-bucket node sort, staged coalesced esrc ============
__global__ __launch_bounds__(256) void finalize_kernel(
    const uint32* __restrict__ tmp, const int* __restrict__ bstart,
    int* __restrict__ row_off, int* __restrict__ esrc)
{
    __shared__ int cnt[256];
    __shared__ int pref[256];
    __shared__ int cur[256];
    __shared__ uint32 stg[STG_MAX];
    int q = blockIdx.x, t = threadIdx.x;
    int start = bstart[q];
    int end = bstart[q + 1];
    int seg = end - start;

    cnt[t] = 0;
    __syncthreads();
    for (int e = start + t; e < end; e += 256)
        atomicAdd(&cnt[tmp[e] >> 17], 1);
    __syncthreads();
    pref[t] = cnt[t];
    __syncthreads();
    for (int off = 1; off < 256; off <<= 1) {
        int x = (t >= off) ? pref[t - off] : 0;
        __syncthreads();
        pref[t] += x;
        __syncthreads();
    }
    {
        int excl = pref[t] - cnt[t];
        int node = q * 256 + t;
        if (node < N_NODES) row_off[node] = start + excl;
        cur[t] = excl;                       // LOCAL offset within segment
    }
    if (q == 0 && t == 0) row_off[N_NODES] = N_EDGES;
    __syncthreads();
    if (seg <= STG_MAX) {
        // stage node-sorted values in LDS, then fully coalesced copy-out
        for (int e = start + t; e < end; e += 256) {
            uint32 u = tmp[e];
            int pos = atomicAdd(&cur[u >> 17], 1);
            stg[pos] = u & 0x1FFFFu;
        }
        __syncthreads();
        for (int i = t; i < seg; i += 256)
            esrc[start + i] = (int)stg[i];
    } else {
        // fallback: direct scattered writes (never expected for this input)
        for (int e = start + t; e < end; e += 256) {
            uint32 u = tmp[e];
            int pos = atomicAdd(&cur[u >> 17], 1);
            esrc[start + pos] = (int)(u & 0x1FFFFu);
        }
    }
}

// ============ layer-1 aggregate: gather y1, epilogue (1+eps)self+agg+b, relu ============
__global__ __launch_bounds__(256) void aggregate_kernel(
    const uint4* __restrict__ y4,      // [N*8] uint4 (8 per node row)
    const int* __restrict__ row_off,   // [N+1]
    const int* __restrict__ esrc,      // [E]
    const float* __restrict__ b,       // [64]
    const float* __restrict__ eps_p,   // [1]
    uint4* __restrict__ out4)          // [N*8] uint4
{
    int lane = threadIdx.x & 63;
    int wave = threadIdx.x >> 6;
    int grp = lane >> 3;      // node sub-index 0..7
    int w = lane & 7;         // 16B chunk of the 128B row
    int node = blockIdx.x * 32 + wave * 8 + grp;   // grid covers N exactly

    int s0 = row_off[node], s1 = row_off[node + 1];
    float a[8], c[8];
#pragma unroll
    for (int i = 0; i < 8; ++i) { a[i] = 0.f; c[i] = 0.f; }

    int e = s0;
    for (; e + 3 < s1; e += 4) {
        int i0 = esrc[e];
        int i1 = esrc[e + 1];
        int i2 = esrc[e + 2];
        int i3 = esrc[e + 3];
        uint4 v0 = y4[(size_t)i0 * 8 + w];
        uint4 v1 = y4[(size_t)i1 * 8 + w];
        uint4 v2 = y4[(size_t)i2 * 8 + w];
        uint4 v3 = y4[(size_t)i3 * 8 + w];
        acc8(a, v0);
        acc8(c, v1);
        acc8(a, v2);
        acc8(c, v3);
    }
    for (; e < s1; ++e) {
        uint4 v0 = y4[(size_t)esrc[e] * 8 + w];
        acc8(a, v0);
    }
#pragma unroll
    for (int i = 0; i < 8; ++i) a[i] += c[i];

    uint4 sv = y4[(size_t)node * 8 + w];
    float s[8];
    bf2x(sv.x, s[0], s[1]);
    bf2x(sv.y, s[2], s[3]);
    bf2x(sv.z, s[4], s[5]);
    bf2x(sv.w, s[6], s[7]);
    float ep1 = 1.0f + eps_p[0];
    float4 b0 = *(const float4*)&b[w * 8];
    float4 b1 = *(const float4*)&b[w * 8 + 4];
    float r0 = fmaxf(fmaf(ep1, s[0], a[0]) + b0.x, 0.0f);
    float r1 = fmaxf(fmaf(ep1, s[1], a[1]) + b0.y, 0.0f);
    float r2 = fmaxf(fmaf(ep1, s[2], a[2]) + b0.z, 0.0f);
    float r3 = fmaxf(fmaf(ep1, s[3], a[3]) + b0.w, 0.0f);
    float r4 = fmaxf(fmaf(ep1, s[4], a[4]) + b1.x, 0.0f);
    float r5 = fmaxf(fmaf(ep1, s[5], a[5]) + b1.y, 0.0f);
    float r6 = fmaxf(fmaf(ep1, s[6], a[6]) + b1.z, 0.0f);
    float r7 = fmaxf(fmaf(ep1, s[7], a[7]) + b1.w, 0.0f);
    out4[(size_t)node * 8 + w] =
        make_uint4(pk2(r0, r1), pk2(r2, r3), pk2(r4, r5), pk2(r6, r7));
}

// ============ fused layers 2/3: gather h, z=(1+eps)self+agg, MFMA z@W, +b, relu ============
__global__ __launch_bounds__(256) void agg_gemm_fused_kernel(
    const uint4* __restrict__ h4,      // [N*8] uint4 — h rows (bf16, 64 feats)
    const int* __restrict__ row_off,   // [N+1]
    const int* __restrict__ esrc,      // [E]
    const ushort16* __restrict__ Wt,   // [64][64] bf16 (Wt[n][k] = W[k][n])
    const float* __restrict__ bias,    // [64]
    const float* __restrict__ eps_p,   // [1]
    ushort16* __restrict__ hout)       // [N, 64] bf16
{
    __shared__ __align__(16) ushort16 zl[4][16][72];   // per-wave z, row padded to 72
    int lane = threadIdx.x & 63;
    int wave = threadIdx.x >> 6;
    int g = lane >> 2;        // node sub-index 0..15
    int c = lane & 3;         // 32B chunk of the 128B row
    int node0 = blockIdx.x * 64 + wave * 16;
    if (node0 >= N_NODES) return;        // wave-uniform (N % 16 == 0)
    int node = node0 + g;

    int s0 = row_off[node], s1 = row_off[node + 1];
    float a[16], d[16];
#pragma unroll
    for (int i = 0; i < 16; ++i) { a[i] = 0.f; d[i] = 0.f; }

    const size_t cb = (size_t)c * 2;     // chunk offset in uint4 units
    int e = s0;
    for (; e + 3 < s1; e += 4) {
        int i0 = esrc[e];
        int i1 = esrc[e + 1];
        int i2 = esrc[e + 2];
        int i3 = esrc[e + 3];
        uint4 v0a = h4[(size_t)i0 * 8 + cb], v0b = h4[(size_t)i0 * 8 + cb + 1];
        uint4 v1a = h4[(size_t)i1 * 8 + cb], v1b = h4[(size_t)i1 * 8 + cb + 1];
        uint4 v2a = h4[(size_t)i2 * 8 + cb], v2b = h4[(size_t)i2 * 8 + cb + 1];
        uint4 v3a = h4[(size_t)i3 * 8 + cb], v3b = h4[(size_t)i3 * 8 + cb + 1];
        acc8(a, v0a); acc8(a + 8, v0b);
        acc8(d, v1a); acc8(d + 8, v1b);
        acc8(a, v2a); acc8(a + 8, v2b);
        acc8(d, v3a); acc8(d + 8, v3b);
    }
    for (; e < s1; ++e) {
        int i0 = esrc[e];
        uint4 va = h4[(size_t)i0 * 8 + cb], vb = h4[(size_t)i0 * 8 + cb + 1];
        acc8(a, va); acc8(a + 8, vb);
    }
#pragma unroll
    for (int i = 0; i < 16; ++i) a[i] += d[i];

    // z = (1+eps)*self + agg
    uint4 sva = h4[(size_t)node * 8 + cb], svb = h4[(size_t)node * 8 + cb + 1];
    float s[16];
    bf2x(sva.x, s[0], s[1]);  bf2x(sva.y, s[2], s[3]);
    bf2x(sva.z, s[4], s[5]);  bf2x(sva.w, s[6], s[7]);
    bf2x(svb.x, s[8], s[9]);  bf2x(svb.y, s[10], s[11]);
    bf2x(svb.z, s[12], s[13]); bf2x(svb.w, s[14], s[15]);
    float ep1 = 1.0f + eps_p[0];
    float z[16];
#pragma unroll
    for (int i = 0; i < 16; ++i) z[i] = fmaf(ep1, s[i], a[i]);

    // pack z -> per-wave LDS (features c*16 .. c*16+15 of node g)
    uint4 pA = make_uint4(pk2(z[0], z[1]), pk2(z[2], z[3]),
                          pk2(z[4], z[5]), pk2(z[6], z[7]));
    uint4 pB = make_uint4(pk2(z[8], z[9]), pk2(z[10], z[11]),
                          pk2(z[12], z[13]), pk2(z[14], z[15]));
    *(uint4*)&zl[wave][g][c * 16] = pA;
    *(uint4*)&zl[wave][g][c * 16 + 8] = pB;

    // MFMA: 16 nodes x 64 feats, K=64
    int col = lane & 15, quad = lane >> 4;
    short8 a0 = *(const short8*)&zl[wave][col][quad * 8];        // k-tile 0
    short8 a1 = *(const short8*)&zl[wave][col][32 + quad * 8];   // k-tile 1

    f32x4 acc[4];
#pragma unroll
    for (int nt = 0; nt < 4; ++nt)
#pragma unroll
        for (int r = 0; r < 4; ++r) acc[nt][r] = 0.0f;

#pragma unroll
    for (int nt = 0; nt < 4; ++nt) {
        const ushort16* wr = &Wt[(size_t)(nt * 16 + col) * 64 + quad * 8];
        short8 b0 = *(const short8*)&wr[0];
        short8 b1 = *(const short8*)&wr[32];
        acc[nt] = __builtin_amdgcn_mfma_f32_16x16x32_bf16(a0, b0, acc[nt], 0, 0, 0);
        acc[nt] = __builtin_amdgcn_mfma_f32_16x16x32_bf16(a1, b1, acc[nt], 0, 0, 0);
    }

    // epilogue: +bias, relu, bf16 store. feature = nt*16+col, node = node0+quad*4+r
#pragma unroll
    for (int nt = 0; nt < 4; ++nt) {
        float bl = bias[nt * 16 + col];
#pragma unroll
        for (int r = 0; r < 4; ++r) {
            int nd = node0 + quad * 4 + r;
            hout[(size_t)nd * 64 + nt * 16 + col] =
                f2bf(fmaxf(acc[nt][r] + bl, 0.0f));
        }
    }
}

// ============ mean-pool (sorted batch, binary search, bf16 h) + head MLP ============
__global__ __launch_bounds__(256) void pool_head_kernel(
    const uint32* __restrict__ hb,    // [N, 32] bf16x2 words
    const int* __restrict__ batch,    // [N], sorted
    const float* __restrict__ Wf,     // [64, 10]
    const float* __restrict__ bfv,    // [10]
    const float* __restrict__ Wl,     // [10]
    const float* __restrict__ blv,    // [1]
    float* __restrict__ out)          // [G]
{
    __shared__ float red[4][64];
    __shared__ float pooled[64];
    __shared__ float hid[10];
    int g = blockIdx.x;
    int t = threadIdx.x;
    int lo = 0, hi = N_NODES;
    while (lo < hi) { int mid = (lo + hi) >> 1; if (batch[mid] < g) lo = mid + 1; else hi = mid; }
    int start = lo;
    hi = N_NODES;
    while (lo < hi) { int mid = (lo + hi) >> 1; if (batch[mid] < g + 1) lo = mid + 1; else hi = mid; }
    int end = lo;

    int c = t & 63, nl = t >> 6;
    int wd = c >> 1, odd = c & 1;
    float acc = 0.0f;
    for (int i = start + nl; i < end; i += 4) {
        uint32 u = hb[(size_t)i * 32 + wd];
        acc += __uint_as_float(odd ? (u & 0xffff0000u) : (u << 16));
    }
    red[nl][c] = acc;
    __syncthreads();
    if (t < 64) {
        float cnt = (float)(end - start);
        float inv = 1.0f / fmaxf(cnt, 1.0f);
        pooled[t] = (red[0][t] + red[1][t] + red[2][t] + red[3][t]) * inv;
    }
    __syncthreads();
    if (t < 10) {
        float s = bfv[t];
#pragma unroll
        for (int k = 0; k < 64; ++k) s = fmaf(pooled[k], Wf[k * 10 + t], s);
        hid[t] = fmaxf(s, 0.0f);
    }
    __syncthreads();
    if (t == 0) {
        float s = blv[0];
#pragma unroll
        for (int j = 0; j < 10; ++j) s = fmaf(hid[j], Wl[j], s);
        out[g] = s;
    }
}

extern "C" void kernel_launch(void* const* d_in, const int* in_sizes, int n_in,
                              void* d_out, int out_size, void* d_ws, size_t ws_size,
                              hipStream_t stream)
{
    const float* x     = (const float*)d_in[0];
    const int*   ei    = (const int*)  d_in[1];
    const int*   src   = ei;               // edge_index[0]
    const int*   dst   = ei + N_EDGES;     // edge_index[1]
    const int*   batch = (const int*)  d_in[2];
    const float* W1    = (const float*)d_in[3];
    const float* b1    = (const float*)d_in[4];
    const float* W2    = (const float*)d_in[5];
    const float* b2    = (const float*)d_in[6];
    const float* W3    = (const float*)d_in[7];
    const float* b3    = (const float*)d_in[8];
    const float* Wf    = (const float*)d_in[9];
    const float* bfv   = (const float*)d_in[10];
    const float* Wl    = (const float*)d_in[11];
    const float* blv   = (const float*)d_in[12];
    const float* eps1  = (const float*)d_in[13];
    const float* eps2  = (const float*)d_in[14];
    const float* eps3  = (const float*)d_in[15];

    // ---- workspace layout ----
    ushort16* ybA = (ushort16*)d_ws;                       // N*64 bf16
    ushort16* ybB = ybA + (size_t)N_NODES * 64;            // N*64 bf16
    int*   ints = (int*)(ybB + (size_t)N_NODES * 64);
    int*   cnt_g   = ints;                      // NB_C
    int*   bstart  = cnt_g + NB_C;              // NB_C+1
    int*   gcur    = bstart + NB_C + 1;         // NB_C
    int*   row_off = gcur + NB_C;               // N+1
    int*   esrc    = row_off + N_NODES + 1;     // E
    uint32* tmp    = (uint32*)(esrc + N_EDGES); // E
    ushort16* W1t = (ushort16*)(((uintptr_t)(tmp + N_EDGES) + 255) & ~(uintptr_t)255);
    ushort16* W2t = W1t + 64 * 128;
    ushort16* W3t = W2t + 64 * 64;

    const int agg_blk   = N_NODES / 32;          // 3125 (32 nodes/block)
    const int fused_blk = (N_NODES + 63) / 64;   // 1563 (64 nodes/block)

    // ---- zero the global bucket counters (stream-ordered, capture-safe) ----
    hipMemsetAsync(cnt_g, 0, NB_C * sizeof(int), stream);

    // ---- K0: weight pre-pass (must precede gemm1 in a separate launch) ----
    convw_kernel<<<3, 256, 0, stream>>>(W1, W2, W3, W1t, W2t, W3t);

    // ---- K1: count + gemm1 (independent data, co-scheduled) ----
    k1_combined_kernel<<<B1 + GEMM_BLK, 256, 0, stream>>>(
        dst, cnt_g, x, W1t, ybA);

    // ---- K2..K4: scan bins, scatter (atomic reservation), finalize ----
    scan_bins_kernel<<<1, 512, 0, stream>>>(cnt_g, bstart, gcur);
    scatter_kernel<<<B1, 256, 0, stream>>>(src, dst, gcur, tmp);
    finalize_kernel<<<NB_C, 256, 0, stream>>>(tmp, bstart, row_off, esrc);

    // ---- layer 1 aggregate: h1 = GIN(y1) ----
    aggregate_kernel<<<agg_blk, 256, 0, stream>>>(
        (const uint4*)ybA, row_off, esrc, b1, eps1, (uint4*)ybB);

    // ---- layer 2 (fused gather + MFMA transform): h1 -> h2 ----
    agg_gemm_fused_kernel<<<fused_blk, 256, 0, stream>>>(
        (const uint4*)ybB, row_off, esrc, W2t, b2, eps2, ybA);

    // ---- layer 3 (fused): h2 -> h3 ----
    agg_gemm_fused_kernel<<<fused_blk, 256, 0, stream>>>(
        (const uint4*)ybA, row_off, esrc, W3t, b3, eps3, ybB);

    // ---- pool + head ----
    pool_head_kernel<<<N_GRAPHS, 256, 0, stream>>>(
        (const uint32*)ybB, batch, Wf, bfv, Wl, blv, (float*)d_out);
}

// Round 11
// 300.445 us; speedup vs baseline: 1.1538x; 1.1538x over previous
//
#include <hip/hip_runtime.h>

#define N_NODES 100000
#define N_EDGES 1600000
#define N_GRAPHS 1000

#define NB_C 391                 // coarse buckets: dst>>8, 256 nodes each
#define B1   1024                // blocks in count/scatter phases
#define CHUNK_E ((N_EDGES + B1 - 1) / B1)   // 1563
#define MTOT (NB_C * B1)         // 400384
#define STG_MAX 4736             // finalize LDS staging capacity (mean 4096, sd 64)
#define GEMM_BLK ((N_NODES + 63) / 64)      // 1563

typedef unsigned int uint32;
typedef unsigned short ushort16;
typedef __attribute__((ext_vector_type(8))) short short8;   // 8 bf16 (4 VGPRs)
typedef __attribute__((ext_vector_type(4))) float f32x4;    // MFMA C/D

// float -> bf16 with round-to-nearest-even
static __device__ __forceinline__ ushort16 f2bf(float f) {
    uint32 u = __float_as_uint(f);
    u += 0x7fffu + ((u >> 16) & 1u);
    return (ushort16)(u >> 16);
}
static __device__ __forceinline__ uint32 pk2(float a, float b) {
    return (uint32)f2bf(a) | ((uint32)f2bf(b) << 16);
}
// unpack a bf16x2 word into two floats
static __device__ __forceinline__ void bf2x(uint32 v, float& lo, float& hi) {
    lo = __uint_as_float(v << 16);
    hi = __uint_as_float(v & 0xffff0000u);
}
// accumulate a 16B chunk (8 bf16) into a[0..7]
static __device__ __forceinline__ void acc8(float* a, uint4 v) {
    float lo, hi;
    bf2x(v.x, lo, hi); a[0] += lo; a[1] += hi;
    bf2x(v.y, lo, hi); a[2] += lo; a[3] += hi;
    bf2x(v.z, lo, hi); a[4] += lo; a[5] += hi;
    bf2x(v.w, lo, hi); a[6] += lo; a[7] += hi;
}

union CV8 { uint4 u; short8 s; };

// ============ K0: weight pre-pass (separate launch — gemm1 consumes W1t) ============
__global__ __launch_bounds__(256) void convw_kernel(
    const float* __restrict__ W1, const float* __restrict__ W2,
    const float* __restrict__ W3,
    ushort16* __restrict__ W1t, ushort16* __restrict__ W2t,
    ushort16* __restrict__ W3t)
{
    int t = threadIdx.x;
    if (blockIdx.x == 0) {
        for (int i = t; i < 64 * 128; i += 256) {
            int j = i >> 7, k = i & 127;          // W1t[j][k] (64 x 128)
            W1t[i] = f2bf(W1[k * 64 + j]);
        }
    } else if (blockIdx.x == 1) {
        for (int i = t; i < 64 * 64; i += 256) {
            int j = i >> 6, k = i & 63;
            W2t[i] = f2bf(W2[k * 64 + j]);
        }
    } else {
        for (int i = t; i < 64 * 64; i += 256) {
            int j = i >> 6, k = i & 63;
            W3t[i] = f2bf(W3[k * 64 + j]);
        }
    }
}

// ============ K1: count into M matrix (blocks 0..B1-1) + gemm1 (rest) ============
// Disjoint data; convw completed in the prior launch, so gemm1's W1t read is safe.
__global__ __launch_bounds__(256) void k1_combined_kernel(
    const int* __restrict__ dst, int* __restrict__ M,
    const float* __restrict__ x, const ushort16* __restrict__ W1t,
    ushort16* __restrict__ y)
{
    int b = blockIdx.x, t = threadIdx.x;
    if (b < B1) {
        // ---- count: LDS histogram -> M[q][b] ----
        __shared__ int cnt[NB_C];
        for (int q = t; q < NB_C; q += 256) cnt[q] = 0;
        __syncthreads();
        int e0 = b * CHUNK_E;
        int e1 = e0 + CHUNK_E; if (e1 > N_EDGES) e1 = N_EDGES;
        for (int e = e0 + t; e < e1; e += 256)
            atomicAdd(&cnt[dst[e] >> 8], 1);
        __syncthreads();
        for (int q = t; q < NB_C; q += 256) M[q * B1 + b] = cnt[q];
        return;
    }
    // ---- gemm1: y(bf16) = x(fp32->bf16) @ W1, 16 nodes x 64 outs per wave ----
    {
        int lane = t & 63;
        int wave = t >> 6;
        int col = lane & 15, quad = lane >> 4;
        int node0 = (b - B1) * 64 + wave * 16;
        int anode = node0 + col;

        short8 a[4];
        if (anode < N_NODES) {
            const float* xr = &x[(size_t)anode * 128 + quad * 8];
#pragma unroll
            for (int s = 0; s < 4; ++s) {
                float4 v0 = *(const float4*)&xr[s * 32];
                float4 v1 = *(const float4*)&xr[s * 32 + 4];
                CV8 cv;
                cv.u = make_uint4(pk2(v0.x, v0.y), pk2(v0.z, v0.w),
                                  pk2(v1.x, v1.y), pk2(v1.z, v1.w));
                a[s] = cv.s;
            }
        } else {
            short8 z = {0, 0, 0, 0, 0, 0, 0, 0};
#pragma unroll
            for (int s = 0; s < 4; ++s) a[s] = z;
        }

        f32x4 acc[4];
#pragma unroll
        for (int nt = 0; nt < 4; ++nt)
#pragma unroll
            for (int r = 0; r < 4; ++r) acc[nt][r] = 0.0f;

#pragma unroll
        for (int nt = 0; nt < 4; ++nt) {
            const ushort16* wr = &W1t[(size_t)(nt * 16 + col) * 128 + quad * 8];
#pragma unroll
            for (int s = 0; s < 4; ++s) {
                short8 bb8 = *(const short8*)&wr[s * 32];
                acc[nt] = __builtin_amdgcn_mfma_f32_16x16x32_bf16(a[s], bb8, acc[nt], 0, 0, 0);
            }
        }

#pragma unroll
        for (int nt = 0; nt < 4; ++nt)
#pragma unroll
            for (int r = 0; r < 4; ++r) {
                int node = node0 + quad * 4 + r;
                if (node < N_NODES)
                    y[(size_t)node * 64 + nt * 16 + col] = f2bf(acc[nt][r]);
            }
    }
}

#define SCAN_B 1024
#define SCAN_NBLK (MTOT / SCAN_B)   // 391 (exact)

__global__ __launch_bounds__(256) void scanA_kernel(
    const int* __restrict__ in, int* __restrict__ excl, int* __restrict__ bsum)
{
    __shared__ int s[256];
    int b = blockIdx.x, t = threadIdx.x;
    int base = b * SCAN_B + t * 4;
    int v[4];
#pragma unroll
    for (int i = 0; i < 4; ++i) v[i] = (base + i < MTOT) ? in[base + i] : 0;
    int tsum = v[0] + v[1] + v[2] + v[3];
    s[t] = tsum;
    __syncthreads();
    for (int off = 1; off < 256; off <<= 1) {
        int x = (t >= off) ? s[t - off] : 0;
        __syncthreads();
        s[t] += x;
        __syncthreads();
    }
    int run = s[t] - tsum;
#pragma unroll
    for (int i = 0; i < 4; ++i) {
        if (base + i < MTOT) excl[base + i] = run;
        run += v[i];
    }
    if (t == 255) bsum[b] = s[255];
}

__global__ __launch_bounds__(512) void scanB_kernel(int* __restrict__ bsum)
{
    __shared__ int s[512];
    int t = threadIdx.x;
    int v = (t < SCAN_NBLK) ? bsum[t] : 0;
    s[t] = v;
    __syncthreads();
    for (int off = 1; off < 512; off <<= 1) {
        int x = (t >= off) ? s[t - off] : 0;
        __syncthreads();
        s[t] += x;
        __syncthreads();
    }
    if (t < SCAN_NBLK) bsum[t] = s[t] - v;   // exclusive
}

__global__ __launch_bounds__(256) void scanC_kernel(
    const int* __restrict__ excl, const int* __restrict__ bsum,
    int* __restrict__ out)
{
    int b = blockIdx.x, t = threadIdx.x;
    int add = bsum[b];
    int base = b * SCAN_B + t * 4;
#pragma unroll
    for (int i = 0; i < 4; ++i)
        if (base + i < MTOT) out[base + i] = excl[base + i] + add;
}

// ---- scatter: block-local LDS counting sort, coalesced copy-out (Ms-indexed) ----
// Payload: ((dst & 255) << 17) | src   (src < 2^17)
__global__ __launch_bounds__(256) void scatter_kernel(
    const int* __restrict__ src, const int* __restrict__ dst,
    const int* __restrict__ Ms, uint32* __restrict__ tmp)
{
    __shared__ int cnt[NB_C];
    __shared__ int loc[NB_C];
    __shared__ int cur[NB_C];
    __shared__ int msb[NB_C];
    __shared__ int ssum[256];
    __shared__ uint32 staged[CHUNK_E];
    __shared__ unsigned short bkt[CHUNK_E];
    int b = blockIdx.x, t = threadIdx.x;
    int e0 = b * CHUNK_E;
    int e1 = e0 + CHUNK_E; if (e1 > N_EDGES) e1 = N_EDGES;
    int n = e1 - e0;

    for (int q = t; q < NB_C; q += 256) {
        cnt[q] = 0;
        msb[q] = Ms[q * B1 + b];
    }
    __syncthreads();
    for (int e = e0 + t; e < e1; e += 256)
        atomicAdd(&cnt[dst[e] >> 8], 1);
    __syncthreads();
    // parallel exclusive scan over NB_C bins: thread t owns bins {2t, 2t+1}
    int q0 = 2 * t, q1 = 2 * t + 1;
    int c0 = (q0 < NB_C) ? cnt[q0] : 0;
    int c1 = (q1 < NB_C) ? cnt[q1] : 0;
    int pairsum = c0 + c1;
    ssum[t] = pairsum;
    __syncthreads();
    for (int off = 1; off < 256; off <<= 1) {
        int x = (t >= off) ? ssum[t - off] : 0;
        __syncthreads();
        ssum[t] += x;
        __syncthreads();
    }
    int excl = ssum[t] - pairsum;
    if (q0 < NB_C) { loc[q0] = excl; cur[q0] = excl; }
    if (q1 < NB_C) { loc[q1] = excl + c0; cur[q1] = excl + c0; }
    __syncthreads();
    // place edges bucket-sorted into LDS; remember bucket id per slot
    for (int e = e0 + t; e < e1; e += 256) {
        int d = dst[e];
        int q = d >> 8;
        int pos = atomicAdd(&cur[q], 1);
        staged[pos] = ((uint32)(d & 255) << 17) | (uint32)src[e];
        bkt[pos] = (unsigned short)q;
    }
    __syncthreads();
    // copy-out: consecutive lanes -> consecutive global addresses within runs
    for (int i = t; i < n; i += 256) {
        int q = bkt[i];
        tmp[msb[q] + (i - loc[q])] = staged[i];
    }
}

// ---- finalize: per-bucket node sort with LDS-staged coalesced esrc writes ----
__global__ __launch_bounds__(256) void finalize_kernel(
    const uint32* __restrict__ tmp, const int* __restrict__ Ms,
    int* __restrict__ row_off, int* __restrict__ esrc)
{
    __shared__ int cnt[256];
    __shared__ int pref[256];
    __shared__ int cur[256];
    __shared__ uint32 stg[STG_MAX];
    int q = blockIdx.x, t = threadIdx.x;
    int start = Ms[q * B1];
    int end = (q == NB_C - 1) ? N_EDGES : Ms[(q + 1) * B1];
    int seg = end - start;

    cnt[t] = 0;
    __syncthreads();
    for (int e = start + t; e < end; e += 256)
        atomicAdd(&cnt[tmp[e] >> 17], 1);
    __syncthreads();
    pref[t] = cnt[t];
    __syncthreads();
    for (int off = 1; off < 256; off <<= 1) {
        int x = (t >= off) ? pref[t - off] : 0;
        __syncthreads();
        pref[t] += x;
        __syncthreads();
    }
    {
        int excl = pref[t] - cnt[t];
        int node = q * 256 + t;
        if (node < N_NODES) row_off[node] = start + excl;
        cur[t] = excl;                       // LOCAL offset within segment
    }
    if (q == 0 && t == 0) row_off[N_NODES] = N_EDGES;
    __syncthreads();
    if (seg <= STG_MAX) {
        // stage node-sorted values in LDS, then fully coalesced copy-out
        for (int e = start + t; e < end; e += 256) {
            uint32 u = tmp[e];
            int pos = atomicAdd(&cur[u >> 17], 1);
            stg[pos] = u & 0x1FFFFu;
        }
        __syncthreads();
        for (int i = t; i < seg; i += 256)
            esrc[start + i] = (int)stg[i];
    } else {
        // fallback: direct scattered writes (never expected for this input)
        for (int e = start + t; e < end; e += 256) {
            uint32 u = tmp[e];
            int pos = atomicAdd(&cur[u >> 17], 1);
            esrc[start + pos] = (int)(u & 0x1FFFFu);
        }
    }
}

// ============ layer-1 aggregate: gather y1, epilogue (1+eps)self+agg+b, relu ============
__global__ __launch_bounds__(256) void aggregate_kernel(
    const uint4* __restrict__ y4,      // [N*8] uint4 (8 per node row)
    const int* __restrict__ row_off,   // [N+1]
    const int* __restrict__ esrc,      // [E]
    const float* __restrict__ b,       // [64]
    const float* __restrict__ eps_p,   // [1]
    uint4* __restrict__ out4)          // [N*8] uint4
{
    int lane = threadIdx.x & 63;
    int wave = threadIdx.x >> 6;
    int grp = lane >> 3;      // node sub-index 0..7
    int w = lane & 7;         // 16B chunk of the 128B row
    int node = blockIdx.x * 32 + wave * 8 + grp;   // grid covers N exactly

    int s0 = row_off[node], s1 = row_off[node + 1];
    float a[8], c[8];
#pragma unroll
    for (int i = 0; i < 8; ++i) { a[i] = 0.f; c[i] = 0.f; }

    int e = s0;
    for (; e + 3 < s1; e += 4) {
        int i0 = esrc[e];
        int i1 = esrc[e + 1];
        int i2 = esrc[e + 2];
        int i3 = esrc[e + 3];
        uint4 v0 = y4[(size_t)i0 * 8 + w];
        uint4 v1 = y4[(size_t)i1 * 8 + w];
        uint4 v2 = y4[(size_t)i2 * 8 + w];
        uint4 v3 = y4[(size_t)i3 * 8 + w];
        acc8(a, v0);
        acc8(c, v1);
        acc8(a, v2);
        acc8(c, v3);
    }
    for (; e < s1; ++e) {
        uint4 v0 = y4[(size_t)esrc[e] * 8 + w];
        acc8(a, v0);
    }
#pragma unroll
    for (int i = 0; i < 8; ++i) a[i] += c[i];

    uint4 sv = y4[(size_t)node * 8 + w];
    float s[8];
    bf2x(sv.x, s[0], s[1]);
    bf2x(sv.y, s[2], s[3]);
    bf2x(sv.z, s[4], s[5]);
    bf2x(sv.w, s[6], s[7]);
    float ep1 = 1.0f + eps_p[0];
    float4 b0 = *(const float4*)&b[w * 8];
    float4 b1 = *(const float4*)&b[w * 8 + 4];
    float r0 = fmaxf(fmaf(ep1, s[0], a[0]) + b0.x, 0.0f);
    float r1 = fmaxf(fmaf(ep1, s[1], a[1]) + b0.y, 0.0f);
    float r2 = fmaxf(fmaf(ep1, s[2], a[2]) + b0.z, 0.0f);
    float r3 = fmaxf(fmaf(ep1, s[3], a[3]) + b0.w, 0.0f);
    float r4 = fmaxf(fmaf(ep1, s[4], a[4]) + b1.x, 0.0f);
    float r5 = fmaxf(fmaf(ep1, s[5], a[5]) + b1.y, 0.0f);
    float r6 = fmaxf(fmaf(ep1, s[6], a[6]) + b1.z, 0.0f);
    float r7 = fmaxf(fmaf(ep1, s[7], a[7]) + b1.w, 0.0f);
    out4[(size_t)node * 8 + w] =
        make_uint4(pk2(r0, r1), pk2(r2, r3), pk2(r4, r5), pk2(r6, r7));
}

// ============ fused layers 2/3: gather h, z=(1+eps)self+agg, MFMA z@W, +b, relu ============
__global__ __launch_bounds__(256) void agg_gemm_fused_kernel(
    const uint4* __restrict__ h4,      // [N*8] uint4 — h rows (bf16, 64 feats)
    const int* __restrict__ row_off,   // [N+1]
    const int* __restrict__ esrc,      // [E]
    const ushort16* __restrict__ Wt,   // [64][64] bf16 (Wt[n][k] = W[k][n])
    const float* __restrict__ bias,    // [64]
    const float* __restrict__ eps_p,   // [1]
    ushort16* __restrict__ hout)       // [N, 64] bf16
{
    __shared__ __align__(16) ushort16 zl[4][16][72];   // per-wave z, row padded to 72
    int lane = threadIdx.x & 63;
    int wave = threadIdx.x >> 6;
    int g = lane >> 2;        // node sub-index 0..15
    int c = lane & 3;         // 32B chunk of the 128B row
    int node0 = blockIdx.x * 64 + wave * 16;
    if (node0 >= N_NODES) return;        // wave-uniform (N % 16 == 0)
    int node = node0 + g;

    int s0 = row_off[node], s1 = row_off[node + 1];
    float a[16], d[16];
#pragma unroll
    for (int i = 0; i < 16; ++i) { a[i] = 0.f; d[i] = 0.f; }

    const size_t cb = (size_t)c * 2;     // chunk offset in uint4 units
    int e = s0;
    for (; e + 3 < s1; e += 4) {
        int i0 = esrc[e];
        int i1 = esrc[e + 1];
        int i2 = esrc[e + 2];
        int i3 = esrc[e + 3];
        uint4 v0a = h4[(size_t)i0 * 8 + cb], v0b = h4[(size_t)i0 * 8 + cb + 1];
        uint4 v1a = h4[(size_t)i1 * 8 + cb], v1b = h4[(size_t)i1 * 8 + cb + 1];
        uint4 v2a = h4[(size_t)i2 * 8 + cb], v2b = h4[(size_t)i2 * 8 + cb + 1];
        uint4 v3a = h4[(size_t)i3 * 8 + cb], v3b = h4[(size_t)i3 * 8 + cb + 1];
        acc8(a, v0a); acc8(a + 8, v0b);
        acc8(d, v1a); acc8(d + 8, v1b);
        acc8(a, v2a); acc8(a + 8, v2b);
        acc8(d, v3a); acc8(d + 8, v3b);
    }
    for (; e < s1; ++e) {
        int i0 = esrc[e];
        uint4 va = h4[(size_t)i0 * 8 + cb], vb = h4[(size_t)i0 * 8 + cb + 1];
        acc8(a, va); acc8(a + 8, vb);
    }
#pragma unroll
    for (int i = 0; i < 16; ++i) a[i] += d[i];

    // z = (1+eps)*self + agg
    uint4 sva = h4[(size_t)node * 8 + cb], svb = h4[(size_t)node * 8 + cb + 1];
    float s[16];
    bf2x(sva.x, s[0], s[1]);  bf2x(sva.y, s[2], s[3]);
    bf2x(sva.z, s[4], s[5]);  bf2x(sva.w, s[6], s[7]);
    bf2x(svb.x, s[8], s[9]);  bf2x(svb.y, s[10], s[11]);
    bf2x(svb.z, s[12], s[13]); bf2x(svb.w, s[14], s[15]);
    float ep1 = 1.0f + eps_p[0];
    float z[16];
#pragma unroll
    for (int i = 0; i < 16; ++i) z[i] = fmaf(ep1, s[i], a[i]);

    // pack z -> per-wave LDS (features c*16 .. c*16+15 of node g)
    uint4 pA = make_uint4(pk2(z[0], z[1]), pk2(z[2], z[3]),
                          pk2(z[4], z[5]), pk2(z[6], z[7]));
    uint4 pB = make_uint4(pk2(z[8], z[9]), pk2(z[10], z[11]),
                          pk2(z[12], z[13]), pk2(z[14], z[15]));
    *(uint4*)&zl[wave][g][c * 16] = pA;
    *(uint4*)&zl[wave][g][c * 16 + 8] = pB;

    // MFMA: 16 nodes x 64 feats, K=64
    int col = lane & 15, quad = lane >> 4;
    short8 a0 = *(const short8*)&zl[wave][col][quad * 8];        // k-tile 0
    short8 a1 = *(const short8*)&zl[wave][col][32 + quad * 8];   // k-tile 1

    f32x4 acc[4];
#pragma unroll
    for (int nt = 0; nt < 4; ++nt)
#pragma unroll
        for (int r = 0; r < 4; ++r) acc[nt][r] = 0.0f;

#pragma unroll
    for (int nt = 0; nt < 4; ++nt) {
        const ushort16* wr = &Wt[(size_t)(nt * 16 + col) * 64 + quad * 8];
        short8 b0 = *(const short8*)&wr[0];
        short8 b1 = *(const short8*)&wr[32];
        acc[nt] = __builtin_amdgcn_mfma_f32_16x16x32_bf16(a0, b0, acc[nt], 0, 0, 0);
        acc[nt] = __builtin_amdgcn_mfma_f32_16x16x32_bf16(a1, b1, acc[nt], 0, 0, 0);
    }

    // epilogue: +bias, relu, bf16 store. feature = nt*16+col, node = node0+quad*4+r
#pragma unroll
    for (int nt = 0; nt < 4; ++nt) {
        float bl = bias[nt * 16 + col];
#pragma unroll
        for (int r = 0; r < 4; ++r) {
            int nd = node0 + quad * 4 + r;
            hout[(size_t)nd * 64 + nt * 16 + col] =
                f2bf(fmaxf(acc[nt][r] + bl, 0.0f));
        }
    }
}

// ============ mean-pool (sorted batch, binary search, bf16 h) + head MLP ============
__global__ __launch_bounds__(256) void pool_head_kernel(
    const uint32* __restrict__ hb,    // [N, 32] bf16x2 words
    const int* __restrict__ batch,    // [N], sorted
    const float* __restrict__ Wf,     // [64, 10]
    const float* __restrict__ bfv,    // [10]
    const float* __restrict__ Wl,     // [10]
    const float* __restrict__ blv,    // [1]
    float* __restrict__ out)          // [G]
{
    __shared__ float red[4][64];
    __shared__ float pooled[64];
    __shared__ float hid[10];
    int g = blockIdx.x;
    int t = threadIdx.x;
    int lo = 0, hi = N_NODES;
    while (lo < hi) { int mid = (lo + hi) >> 1; if (batch[mid] < g) lo = mid + 1; else hi = mid; }
    int start = lo;
    hi = N_NODES;
    while (lo < hi) { int mid = (lo + hi) >> 1; if (batch[mid] < g + 1) lo = mid + 1; else hi = mid; }
    int end = lo;

    int c = t & 63, nl = t >> 6;
    int wd = c >> 1, odd = c & 1;
    float acc = 0.0f;
    for (int i = start + nl; i < end; i += 4) {
        uint32 u = hb[(size_t)i * 32 + wd];
        acc += __uint_as_float(odd ? (u & 0xffff0000u) : (u << 16));
    }
    red[nl][c] = acc;
    __syncthreads();
    if (t < 64) {
        float cnt = (float)(end - start);
        float inv = 1.0f / fmaxf(cnt, 1.0f);
        pooled[t] = (red[0][t] + red[1][t] + red[2][t] + red[3][t]) * inv;
    }
    __syncthreads();
    if (t < 10) {
        float s = bfv[t];
#pragma unroll
        for (int k = 0; k < 64; ++k) s = fmaf(pooled[k], Wf[k * 10 + t], s);
        hid[t] = fmaxf(s, 0.0f);
    }
    __syncthreads();
    if (t == 0) {
        float s = blv[0];
#pragma unroll
        for (int j = 0; j < 10; ++j) s = fmaf(hid[j], Wl[j], s);
        out[g] = s;
    }
}

extern "C" void kernel_launch(void* const* d_in, const int* in_sizes, int n_in,
                              void* d_out, int out_size, void* d_ws, size_t ws_size,
                              hipStream_t stream)
{
    const float* x     = (const float*)d_in[0];
    const int*   ei    = (const int*)  d_in[1];
    const int*   src   = ei;               // edge_index[0]
    const int*   dst   = ei + N_EDGES;     // edge_index[1]
    const int*   batch = (const int*)  d_in[2];
    const float* W1    = (const float*)d_in[3];
    const float* b1    = (const float*)d_in[4];
    const float* W2    = (const float*)d_in[5];
    const float* b2    = (const float*)d_in[6];
    const float* W3    = (const float*)d_in[7];
    const float* b3    = (const float*)d_in[8];
    const float* Wf    = (const float*)d_in[9];
    const float* bfv   = (const float*)d_in[10];
    const float* Wl    = (const float*)d_in[11];
    const float* blv   = (const float*)d_in[12];
    const float* eps1  = (const float*)d_in[13];
    const float* eps2  = (const float*)d_in[14];
    const float* eps3  = (const float*)d_in[15];

    // ---- workspace layout ----
    ushort16* ybA = (ushort16*)d_ws;                       // N*64 bf16
    ushort16* ybB = ybA + (size_t)N_NODES * 64;            // N*64 bf16
    int*   ints = (int*)(ybB + (size_t)N_NODES * 64);
    int*   M       = ints;                      // MTOT
    int*   Mex     = M + MTOT;                  // MTOT
    int*   Ms      = Mex + MTOT;                // MTOT
    int*   bsum    = Ms + MTOT;                 // 512
    int*   row_off = bsum + 512;                // N+1
    int*   esrc    = row_off + N_NODES + 1;     // E
    uint32* tmp    = (uint32*)(esrc + N_EDGES); // E
    ushort16* W1t = (ushort16*)(((uintptr_t)(tmp + N_EDGES) + 255) & ~(uintptr_t)255);
    ushort16* W2t = W1t + 64 * 128;
    ushort16* W3t = W2t + 64 * 64;

    const int agg_blk   = N_NODES / 32;          // 3125 (32 nodes/block)
    const int fused_blk = (N_NODES + 63) / 64;   // 1563 (64 nodes/block)

    // ---- K0: weight pre-pass (must precede gemm1 in a separate launch) ----
    convw_kernel<<<3, 256, 0, stream>>>(W1, W2, W3, W1t, W2t, W3t);

    // ---- K1: count (M matrix) + gemm1 (independent data, co-scheduled) ----
    k1_combined_kernel<<<B1 + GEMM_BLK, 256, 0, stream>>>(
        dst, M, x, W1t, ybA);

    // ---- scan chain + scatter + finalize (R7-proven) ----
    scanA_kernel<<<SCAN_NBLK, 256, 0, stream>>>(M, Mex, bsum);
    scanB_kernel<<<1, 512, 0, stream>>>(bsum);
    scanC_kernel<<<SCAN_NBLK, 256, 0, stream>>>(Mex, bsum, Ms);
    scatter_kernel<<<B1, 256, 0, stream>>>(src, dst, Ms, tmp);
    finalize_kernel<<<NB_C, 256, 0, stream>>>(tmp, Ms, row_off, esrc);

    // ---- layer 1 aggregate: h1 = GIN(y1) ----
    aggregate_kernel<<<agg_blk, 256, 0, stream>>>(
        (const uint4*)ybA, row_off, esrc, b1, eps1, (uint4*)ybB);

    // ---- layer 2 (fused gather + MFMA transform): h1 -> h2 ----
    agg_gemm_fused_kernel<<<fused_blk, 256, 0, stream>>>(
        (const uint4*)ybB, row_off, esrc, W2t, b2, eps2, ybA);

    // ---- layer 3 (fused): h2 -> h3 ----
    agg_gemm_fused_kernel<<<fused_blk, 256, 0, stream>>>(
        (const uint4*)ybA, row_off, esrc, W3t, b3, eps3, ybB);

    // ---- pool + head ----
    pool_head_kernel<<<N_GRAPHS, 256, 0, stream>>>(
        (const uint32*)ybB, batch, Wf, bfv, Wl, blv, (float*)d_out);
}